// Round 5
// baseline (94.473 us; speedup 1.0000x reference)
//
#include <hip/hip_runtime.h>
#include <hip/hip_bf16.h>

#define KK 32
#define DD 512
#define BB 16
#define NN 4096
#define GRP 128      // tokens per block
#define SUBT 64      // tokens per sub-chunk

typedef __attribute__((ext_vector_type(8))) short short8;
typedef __attribute__((ext_vector_type(4))) float f32x4;

__device__ __forceinline__ unsigned short f2bf(float f) {
    unsigned u = __builtin_bit_cast(unsigned, f);
    u += 0x7fffu + ((u >> 16) & 1u);   // RNE bf16
    return (unsigned short)(u >> 16);
}

// row-dependent XOR swizzle of the [d][tok] bf16 tile (128 B rows):
// phase-A column gathers conflict-free; phase-B b128 row reads near floor.
__device__ __forceinline__ int xswz(int r) {
    return ((r & 7) << 4) ^ (((r >> 3) & 3) << 5);
}

// ---------------- kernel 0: c2[k], s2[k], codes->bf16 ----------------
__global__ __launch_bounds__(256) void k_prep(const float* __restrict__ codes,
                                              const float* __restrict__ scale,
                                              float* __restrict__ c2w,
                                              float* __restrict__ s2w,
                                              unsigned short* __restrict__ codesb) {
    __shared__ float red[KK][8];
    int tid = threadIdx.x;
    int k = tid >> 3, pt = tid & 7;
    const float4* p = reinterpret_cast<const float4*>(codes + k * DD + pt * 64);
    ushort4* cb = reinterpret_cast<ushort4*>(codesb + k * DD + pt * 64);
    float s = 0.f;
#pragma unroll
    for (int i = 0; i < 16; ++i) {
        float4 v = p[i];
        s += v.x * v.x + v.y * v.y + v.z * v.z + v.w * v.w;
        ushort4 h;
        h.x = f2bf(v.x); h.y = f2bf(v.y); h.z = f2bf(v.z); h.w = f2bf(v.w);
        cb[i] = h;
    }
    red[k][pt] = s;
    __syncthreads();
    if (tid < KK) {
        float c2 = 0.f;
#pragma unroll
        for (int j = 0; j < 8; ++j) c2 += red[tid][j];
        c2w[tid] = c2;
        float sc = scale[tid];
        s2w[tid] = sc * sc;
    }
}

// ---------------- fused: per (b, 128-token group), two 64-token sub-chunks ----------------
// 256 threads (4 waves), 64 KB x-tile -> 2 blocks/CU, x read from HBM exactly once.
__global__ __launch_bounds__(256, 2) void k_fused(const float* __restrict__ x,
                                                  const unsigned short* __restrict__ codesb,
                                                  const float* __restrict__ c2w,
                                                  const float* __restrict__ s2w,
                                                  float* __restrict__ part,
                                                  float* __restrict__ sAp) {
    __shared__ unsigned short xt[DD * SUBT];   // 64 KB, swizzled [d][tok]
    __shared__ unsigned short alds[8 * 264];   // A bf16 [n/8][k(33-pad)][n%8]
    __shared__ float x2l[32][64];              // 8 KB
    __shared__ float x2f[64];
    __shared__ float sA_l[4][32];

    int tid = threadIdx.x;
    int lane = tid & 63;
    int w = tid >> 6;            // wave 0..3
    int g = lane >> 4, c = lane & 15;
    int bid = blockIdx.x;
    int b = bid >> 5;
    int grp = bid & 31;

    int sr = tid >> 3;           // staging row-group 0..31
    int sq = tid & 7;            // token octet 0..7
    const float* xb = x + (size_t)b * DD * NN + grp * GRP + sq * 8;
    char* xbp = reinterpret_cast<char*>(xt);

    float s2k0 = s2w[c], s2k1 = s2w[c + 16];
    float c2k0 = c2w[c], c2k1 = c2w[c + 16];

    f32x4 accB[2][8] = {};       // [kt][dt] -- 64 VGPR, persists across sub-chunks
    float pA0 = 0.f, pA1 = 0.f;

    for (int sc = 0; sc < 2; ++sc) {
        if (sc) __syncthreads();             // guard xt/alds vs previous phase B
        const float* xs = xb + sc * SUBT;
        float x2p[8] = {0.f, 0.f, 0.f, 0.f, 0.f, 0.f, 0.f, 0.f};

        // ---- stage full 512d x 64tok tile (32 float4 loads/thread) + exact fp32 x2
#pragma unroll 8
        for (int it = 0; it < 16; ++it) {
            int r = it * 32 + sr;
            const float* pr = xs + (size_t)r * NN;
            float4 v0 = *reinterpret_cast<const float4*>(pr);
            float4 v1 = *reinterpret_cast<const float4*>(pr + 4);
            x2p[0] += v0.x * v0.x; x2p[1] += v0.y * v0.y;
            x2p[2] += v0.z * v0.z; x2p[3] += v0.w * v0.w;
            x2p[4] += v1.x * v1.x; x2p[5] += v1.y * v1.y;
            x2p[6] += v1.z * v1.z; x2p[7] += v1.w * v1.w;
            short8 h;
            h[0] = (short)f2bf(v0.x); h[1] = (short)f2bf(v0.y);
            h[2] = (short)f2bf(v0.z); h[3] = (short)f2bf(v0.w);
            h[4] = (short)f2bf(v1.x); h[5] = (short)f2bf(v1.y);
            h[6] = (short)f2bf(v1.z); h[7] = (short)f2bf(v1.w);
            *reinterpret_cast<short8*>(xbp + (((r << 7) + (sq << 4)) ^ xswz(r))) = h;
        }
#pragma unroll
        for (int i = 0; i < 8; ++i) x2l[sr][sq * 8 + i] = x2p[i];
        __syncthreads();                     // xt + x2l ready

        if (tid < 64) {
            float ss = 0.f;
#pragma unroll
            for (int j = 0; j < 32; ++j) ss += x2l[j][tid];
            x2f[tid] = ss;
        }

        // ---- phase A: dist MFMA (x-frag column gathers from swizzled tile)
        f32x4 accA[2] = {};
#pragma unroll
        for (int it = 0; it < 16; ++it) {
            short8 af;
#pragma unroll
            for (int j = 0; j < 8; ++j) {
                int r = it * 32 + g * 8 + j;
                af[j] = *reinterpret_cast<const short*>(
                    xbp + (((r << 7) + ((w * 16 + c) << 1)) ^ xswz(r)));
            }
            short8 b0 = *reinterpret_cast<const short8*>(codesb + (c << 9) + it * 32 + (g << 3));
            short8 b1 = *reinterpret_cast<const short8*>(codesb + ((c + 16) << 9) + it * 32 + (g << 3));
            accA[0] = __builtin_amdgcn_mfma_f32_16x16x32_bf16(af, b0, accA[0], 0, 0, 0);
            accA[1] = __builtin_amdgcn_mfma_f32_16x16x32_bf16(af, b1, accA[1], 0, 0, 0);
        }
        __syncthreads();                     // x2f ready

        // ---- softmax over k, write A to LDS
#pragma unroll
        for (int r = 0; r < 4; ++r) {
            int tloc = w * 16 + g * 4 + r;
            float x2r = x2f[tloc];
            float d0v = s2k0 * (x2r - 2.f * accA[0][r] + c2k0);
            float d1v = s2k1 * (x2r - 2.f * accA[1][r] + c2k1);
            float m = fmaxf(d0v, d1v);
            m = fmaxf(m, __shfl_xor(m, 1));
            m = fmaxf(m, __shfl_xor(m, 2));
            m = fmaxf(m, __shfl_xor(m, 4));
            m = fmaxf(m, __shfl_xor(m, 8));
            float p0 = __expf(d0v - m), p1 = __expf(d1v - m);
            float ss = p0 + p1;
            ss += __shfl_xor(ss, 1);
            ss += __shfl_xor(ss, 2);
            ss += __shfl_xor(ss, 4);
            ss += __shfl_xor(ss, 8);
            float inv = 1.0f / ss;
            float a0 = p0 * inv, a1 = p1 * inv;
            alds[(tloc >> 3) * 264 + c * 8 + (tloc & 7)] = f2bf(a0);
            alds[(tloc >> 3) * 264 + (c + 16) * 8 + (tloc & 7)] = f2bf(a1);
            pA0 += a0;
            pA1 += a1;
        }
        __syncthreads();                     // alds ready

        // ---- phase B: e += A^T x from LDS (M=d rows, N=k cols, K=n)
#pragma unroll
        for (int ns = 0; ns < 2; ++ns) {
            int n0 = ns * 32;
            short8 ba0 = *reinterpret_cast<const short8*>(&alds[((n0 >> 3) + g) * 264 + c * 8]);
            short8 ba1 = *reinterpret_cast<const short8*>(&alds[((n0 >> 3) + g) * 264 + c * 8 + 128]);
#pragma unroll
            for (int dt = 0; dt < 8; ++dt) {
                int r = (w * 8 + dt) * 16 + c;
                short8 ax = *reinterpret_cast<const short8*>(
                    xbp + (((r << 7) + ((n0 + g * 8) << 1)) ^ xswz(r)));
                accB[0][dt] = __builtin_amdgcn_mfma_f32_16x16x32_bf16(ax, ba0, accB[0][dt], 0, 0, 0);
                accB[1][dt] = __builtin_amdgcn_mfma_f32_16x16x32_bf16(ax, ba1, accB[1][dt], 0, 0, 0);
            }
        }
    }

    // ---- epilogue: sA partial + e-partial (no atomics)
    pA0 += __shfl_xor(pA0, 16); pA0 += __shfl_xor(pA0, 32);
    pA1 += __shfl_xor(pA1, 16); pA1 += __shfl_xor(pA1, 32);
    __syncthreads();
    if (lane < 16) {
        sA_l[w][c] = pA0;
        sA_l[w][c + 16] = pA1;
    }
    __syncthreads();
    if (tid < 32) {
        float ss = sA_l[0][tid] + sA_l[1][tid] + sA_l[2][tid] + sA_l[3][tid];
        sAp[(b * 32 + grp) * KK + tid] = ss;
    }
    float* pp = part + (size_t)(b * 32 + grp) * KK * DD;
#pragma unroll
    for (int kt = 0; kt < 2; ++kt)
#pragma unroll
        for (int dt = 0; dt < 8; ++dt) {
            float4 v = {accB[kt][dt][0], accB[kt][dt][1], accB[kt][dt][2], accB[kt][dt][3]};
            *reinterpret_cast<float4*>(pp + (kt * 16 + c) * DD + (w * 8 + dt) * 16 + g * 4) = v;
        }
}

// ---------------- reduce: out = sum_{32 chunks} part - sA*codes ----------------
__global__ __launch_bounds__(256) void k_red(const float* __restrict__ part,
                                             const float* __restrict__ sAp,
                                             const float* __restrict__ codes,
                                             float* __restrict__ out) {
    int bid = blockIdx.x;        // b*32 + k
    int b = bid >> 5, k = bid & 31;
    int tid = threadIdx.x;
    int d = tid * 2;
    float sA = 0.f;
    for (int cc = 0; cc < 32; ++cc) sA += sAp[(b * 32 + cc) * KK + k];   // uniform -> s_loads
    const float* pb = part + (size_t)b * 32 * KK * DD + k * DD + d;
    float s0 = 0.f, s1 = 0.f;
#pragma unroll
    for (int cc = 0; cc < 32; ++cc) {
        float2 v = *reinterpret_cast<const float2*>(pb + (size_t)cc * KK * DD);
        s0 += v.x; s1 += v.y;
    }
    float2 cd = *reinterpret_cast<const float2*>(codes + k * DD + d);
    float2 o;
    o.x = s0 - sA * cd.x;
    o.y = s1 - sA * cd.y;
    *reinterpret_cast<float2*>(out + ((size_t)b * KK + k) * DD + d) = o;
}

extern "C" void kernel_launch(void* const* d_in, const int* in_sizes, int n_in,
                              void* d_out, int out_size, void* d_ws, size_t ws_size,
                              hipStream_t stream) {
    const float* x = (const float*)d_in[0];
    const float* codes = (const float*)d_in[1];
    const float* scale = (const float*)d_in[2];
    float* out = (float*)d_out;
    float* ws = (float*)d_ws;

    float* sAp = ws;                                        // 16*32*32 = 16384 f
    float* c2w = ws + 16384;                                // 32
    float* s2w = ws + 16416;                                // 32
    unsigned short* codesb = (unsigned short*)(ws + 16448); // 32 KB bf16
    float* part = ws + 16448 + 8192;                        // 512*32*512 f = 33.6 MB

    k_prep<<<1, 256, 0, stream>>>(codes, scale, c2w, s2w, codesb);
    k_fused<<<BB * 32, 256, 0, stream>>>(x, codesb, c2w, s2w, part, sAp);
    k_red<<<BB * KK, 256, 0, stream>>>(part, sAp, codes, out);
}

// Round 6
// 65.898 us; speedup vs baseline: 1.4336x; 1.4336x over previous
//
#include <hip/hip_runtime.h>
#include <hip/hip_bf16.h>

#define KK 32
#define DD 512
#define BB 16
#define NN 4096

typedef __attribute__((ext_vector_type(8))) short short8;
typedef __attribute__((ext_vector_type(4))) float f32x4;

__device__ __forceinline__ unsigned short f2bf(float f) {
    unsigned u = __builtin_bit_cast(unsigned, f);
    u += 0x7fffu + ((u >> 16) & 1u);   // RNE bf16
    return (unsigned short)(u >> 16);
}

// ---------------- kernel 0: c2[k], s2[k], codes->bf16 ----------------
__global__ __launch_bounds__(256) void k_prep(const float* __restrict__ codes,
                                              const float* __restrict__ scale,
                                              float* __restrict__ c2w,
                                              float* __restrict__ s2w,
                                              unsigned short* __restrict__ codesb) {
    __shared__ float red[KK][8];
    int tid = threadIdx.x;
    int k = tid >> 3, pt = tid & 7;
    const float4* p = reinterpret_cast<const float4*>(codes + k * DD + pt * 64);
    ushort4* cb = reinterpret_cast<ushort4*>(codesb + k * DD + pt * 64);
    float s = 0.f;
#pragma unroll
    for (int i = 0; i < 16; ++i) {
        float4 v = p[i];
        s += v.x * v.x + v.y * v.y + v.z * v.z + v.w * v.w;
        ushort4 h;
        h.x = f2bf(v.x); h.y = f2bf(v.y); h.z = f2bf(v.z); h.w = f2bf(v.w);
        cb[i] = h;
    }
    red[k][pt] = s;
    __syncthreads();
    if (tid < KK) {
        float c2 = 0.f;
#pragma unroll
        for (int j = 0; j < 8; ++j) c2 += red[tid][j];
        c2w[tid] = c2;
        float sc = scale[tid];
        s2w[tid] = sc * sc;
    }
}

// ---------------- pass A: softmax assignments A + bf16 x relay ----------------
// 256 threads (4 waves), 64 tokens/block, grid = 16*64 = 1024 (4 blocks/CU).
__global__ __launch_bounds__(256) void k_assign(const float* __restrict__ x,
                                                const unsigned short* __restrict__ codesb,
                                                const float* __restrict__ c2w,
                                                const float* __restrict__ s2w,
                                                unsigned short* __restrict__ Aout,
                                                unsigned short* __restrict__ xrel,
                                                float* __restrict__ sAp) {
    __shared__ unsigned short xt[2][32 * 64];   // 2 x 4 KB, swizzled [d][tok]
    __shared__ float x2_lds[16][64];
    __shared__ float x2f[64];
    __shared__ float sA_lds[4][32];

    int tid = threadIdx.x;
    int lane = tid & 63;
    int w = tid >> 6;          // wave -> 16 tokens
    int g = lane >> 4, c = lane & 15;
    int bid = blockIdx.x;
    int b = bid >> 6;
    int chunk = bid & 63;
    int tok_base = chunk << 6;

    int srow = tid >> 4;       // 0..15
    int q = tid & 15;          // float4 token-column
    const float* xb = x + (size_t)b * DD * NN + tok_base + q * 4;
    unsigned short* xrb = xrel + (size_t)b * DD * NN + tok_base + q * 4;

    float s2k0 = s2w[c], s2k1 = s2w[c + 16];
    float c2k0 = c2w[c], c2k1 = c2w[c + 16];

    f32x4 acc[2] = {};
    float x2p0 = 0.f, x2p1 = 0.f, x2p2 = 0.f, x2p3 = 0.f;
    float4 ld0, ld1;

    auto issue = [&](int it) {
        ld0 = *reinterpret_cast<const float4*>(xb + (size_t)(it * 32 + srow) * NN);
        ld1 = *reinterpret_cast<const float4*>(xb + (size_t)(it * 32 + srow + 16) * NN);
    };
    auto write_tile = [&](int buf, int it) {
        char* bp = reinterpret_cast<char*>(&xt[buf][0]);
        x2p0 += ld0.x * ld0.x + ld1.x * ld1.x;
        x2p1 += ld0.y * ld0.y + ld1.y * ld1.y;
        x2p2 += ld0.z * ld0.z + ld1.z * ld1.z;
        x2p3 += ld0.w * ld0.w + ld1.w * ld1.w;
        ushort4 h0, h1;
        h0.x = f2bf(ld0.x); h0.y = f2bf(ld0.y); h0.z = f2bf(ld0.z); h0.w = f2bf(ld0.w);
        h1.x = f2bf(ld1.x); h1.y = f2bf(ld1.y); h1.z = f2bf(ld1.z); h1.w = f2bf(ld1.w);
        int r0 = srow, r1 = srow + 16;
        *reinterpret_cast<ushort4*>(bp + ((r0 << 7) + (q << 3) ^ (((r0 >> 3) & 3) << 5))) = h0;
        *reinterpret_cast<ushort4*>(bp + ((r1 << 7) + (q << 3) ^ (((r1 >> 3) & 3) << 5))) = h1;
        // bf16 relay (linear [d][n]) for pass B
        *reinterpret_cast<ushort4*>(xrb + (size_t)(it * 32 + srow) * NN) = h0;
        *reinterpret_cast<ushort4*>(xrb + (size_t)(it * 32 + srow + 16) * NN) = h1;
    };

    issue(0);
    write_tile(0, 0);
    __syncthreads();

    for (int it = 0; it < 16; ++it) {
        int cur = it & 1;
        if (it < 15) issue(it + 1);
        const char* bp = reinterpret_cast<const char*>(&xt[cur][0]);
        short8 af;
#pragma unroll
        for (int j = 0; j < 8; ++j) {
            int row = g * 8 + j;
            af[j] = *reinterpret_cast<const short*>(
                bp + (((row << 7) + ((w * 16 + c) << 1)) ^ (((row >> 3) & 3) << 5)));
        }
        short8 b0 = *reinterpret_cast<const short8*>(codesb + (c << 9) + it * 32 + (g << 3));
        short8 b1 = *reinterpret_cast<const short8*>(codesb + ((c + 16) << 9) + it * 32 + (g << 3));
        acc[0] = __builtin_amdgcn_mfma_f32_16x16x32_bf16(af, b0, acc[0], 0, 0, 0);
        acc[1] = __builtin_amdgcn_mfma_f32_16x16x32_bf16(af, b1, acc[1], 0, 0, 0);
        if (it < 15) write_tile(cur ^ 1, it + 1);
        __syncthreads();
    }

    *reinterpret_cast<float4*>(&x2_lds[srow][q * 4]) = make_float4(x2p0, x2p1, x2p2, x2p3);
    __syncthreads();
    if (tid < 64) {
        float ss = 0.f;
#pragma unroll
        for (int j = 0; j < 16; ++j) ss += x2_lds[j][tid];
        x2f[tid] = ss;
    }
    __syncthreads();

    unsigned short* Ab = Aout + (size_t)b * NN * KK;
    float pA0 = 0.f, pA1 = 0.f;
#pragma unroll
    for (int r = 0; r < 4; ++r) {
        int tloc = w * 16 + g * 4 + r;
        float x2r = x2f[tloc];
        float d0v = s2k0 * (x2r - 2.f * acc[0][r] + c2k0);
        float d1v = s2k1 * (x2r - 2.f * acc[1][r] + c2k1);
        float m = fmaxf(d0v, d1v);
        m = fmaxf(m, __shfl_xor(m, 1));
        m = fmaxf(m, __shfl_xor(m, 2));
        m = fmaxf(m, __shfl_xor(m, 4));
        m = fmaxf(m, __shfl_xor(m, 8));
        float p0 = __expf(d0v - m), p1 = __expf(d1v - m);
        float ss = p0 + p1;
        ss += __shfl_xor(ss, 1);
        ss += __shfl_xor(ss, 2);
        ss += __shfl_xor(ss, 4);
        ss += __shfl_xor(ss, 8);
        float inv = 1.0f / ss;
        float a0 = p0 * inv, a1 = p1 * inv;
        int n = tok_base + tloc;
        unsigned short* pa = Ab + ((size_t)(n >> 3) << 8) + (n & 7);   // [n/8][k=32][n%8]
        pa[c * 8] = f2bf(a0);
        pa[(c + 16) * 8] = f2bf(a1);
        pA0 += a0;
        pA1 += a1;
    }
    pA0 += __shfl_xor(pA0, 16); pA0 += __shfl_xor(pA0, 32);
    pA1 += __shfl_xor(pA1, 16); pA1 += __shfl_xor(pA1, 32);
    if (lane < 16) {
        sA_lds[w][c] = pA0;
        sA_lds[w][c + 16] = pA1;
    }
    __syncthreads();
    if (tid < 32) {
        float ss = sA_lds[0][tid] + sA_lds[1][tid] + sA_lds[2][tid] + sA_lds[3][tid];
        sAp[(b * 64 + chunk) * KK + tid] = ss;
    }
}

// ---------------- pass B: e-partials per (b, 512-tok chunk, 128-d slice) ----------------
// 512 threads (8 waves), no LDS, no barriers, no atomics; reads bf16 relay.
// grid = 16 b * 8 nc * 4 dh = 512
__global__ __launch_bounds__(512) void k_agg(const unsigned short* __restrict__ xrel,
                                             const unsigned short* __restrict__ Ain,
                                             float* __restrict__ part) {
    int tid = threadIdx.x;
    int lane = tid & 63;
    int w = tid >> 6;
    int g = lane >> 4, c = lane & 15;
    int bid = blockIdx.x;
    int b = bid >> 5;
    int nc = (bid >> 2) & 7;
    int dh = bid & 3;

    int dr = dh * 128 + w * 16 + c;                       // this lane's d row
    const unsigned short* xr = xrel + ((size_t)b * DD + dr) * NN;
    const unsigned short* Ab = Ain + (size_t)b * NN * KK;

    f32x4 acc0 = {}, acc1 = {};
#pragma unroll 4
    for (int ns = 0; ns < 16; ++ns) {
        int n0 = nc * 512 + ns * 32 + g * 8;
        const unsigned short* pa = Ab + ((size_t)(n0 >> 3) << 8);
        short8 a0 = *reinterpret_cast<const short8*>(pa + c * 8);          // k = c
        short8 a1 = *reinterpret_cast<const short8*>(pa + c * 8 + 128);    // k = c+16
        short8 xf = *reinterpret_cast<const short8*>(xr + n0);             // contiguous 16B
        acc0 = __builtin_amdgcn_mfma_f32_16x16x32_bf16(a0, xf, acc0, 0, 0, 0);
        acc1 = __builtin_amdgcn_mfma_f32_16x16x32_bf16(a1, xf, acc1, 0, 0, 0);
    }
    float* pp = part + (size_t)(b * 8 + nc) * KK * DD;
#pragma unroll
    for (int r = 0; r < 4; ++r) {
        pp[(g * 4 + r) * DD + dr] = acc0[r];
        pp[(16 + g * 4 + r) * DD + dr] = acc1[r];
    }
}

// ---------------- reduce: out = sum_{8 chunks} part - sA*codes ----------------
__global__ __launch_bounds__(256) void k_red(const float* __restrict__ part,
                                             const float* __restrict__ sAp,
                                             const float* __restrict__ codes,
                                             float* __restrict__ out) {
    int bid = blockIdx.x;        // b*32 + k
    int b = bid >> 5, k = bid & 31;
    int tid = threadIdx.x;
    int d = tid * 2;
    float sA = 0.f;
    for (int cc = 0; cc < 64; ++cc) sA += sAp[(b * 64 + cc) * KK + k];   // uniform -> s_loads
    const float* pb = part + (size_t)b * 8 * KK * DD + k * DD + d;
    float s0 = 0.f, s1 = 0.f;
#pragma unroll
    for (int cc = 0; cc < 8; ++cc) {
        float2 v = *reinterpret_cast<const float2*>(pb + (size_t)cc * KK * DD);
        s0 += v.x; s1 += v.y;
    }
    float2 cd = *reinterpret_cast<const float2*>(codes + k * DD + d);
    float2 o;
    o.x = s0 - sA * cd.x;
    o.y = s1 - sA * cd.y;
    *reinterpret_cast<float2*>(out + ((size_t)b * KK + k) * DD + d) = o;
}

extern "C" void kernel_launch(void* const* d_in, const int* in_sizes, int n_in,
                              void* d_out, int out_size, void* d_ws, size_t ws_size,
                              hipStream_t stream) {
    const float* x = (const float*)d_in[0];
    const float* codes = (const float*)d_in[1];
    const float* scale = (const float*)d_in[2];
    float* out = (float*)d_out;
    float* ws = (float*)d_ws;

    float* sAp = ws;                                          // 16*64*32 = 32768 f
    float* c2w = ws + 32768;                                  // 32
    float* s2w = ws + 32800;                                  // 32
    unsigned short* codesb = (unsigned short*)(ws + 32832);   // 32 KB bf16
    unsigned short* Abuf = (unsigned short*)(ws + 41024);     // B*N*K bf16 ~4.2 MB
    unsigned short* xrel = (unsigned short*)(ws + 1089600);   // B*D*N bf16 = 67 MB
    float* part = ws + 17866816;                              // 16*8*32*512 f = 8.4 MB

    k_prep<<<1, 256, 0, stream>>>(codes, scale, c2w, s2w, codesb);
    k_assign<<<BB * 64, 256, 0, stream>>>(x, codesb, c2w, s2w, Abuf, xrel, sAp);
    k_agg<<<BB * 8 * 4, 512, 0, stream>>>(xrel, Abuf, part);
    k_red<<<BB * KK, 256, 0, stream>>>(part, sAp, codes, out);
}